// Round 2
// baseline (2077.424 us; speedup 1.0000x reference)
//
#include <hip/hip_runtime.h>
#include <math.h>

#define DEV static __device__ __forceinline__

DEV void load8(const float* p, float* v) {
    float4 a = *(const float4*)p;
    float4 b = *(const float4*)(p + 4);
    v[0] = a.x; v[1] = a.y; v[2] = a.z; v[3] = a.w;
    v[4] = b.x; v[5] = b.y; v[6] = b.z; v[7] = b.w;
}

// ---------- f32 GEMM: C[m,n] = sum_k A[m,k]*W[n,k] + bias[n]; N=K=512 ----------
// Strict ascending-k, single-accumulator f32 FMA: matches BLAS/Eigen micro-kernel
// accumulation semantics (the references' likely bit pattern).
__global__ __launch_bounds__(256) void gemm_nt512(
    const float* __restrict__ A, const float* __restrict__ W,
    const float* __restrict__ bias, float* __restrict__ C)
{
    constexpr int BK = 32, NK = 512;
    __shared__ float As[BK][64 + 4];
    __shared__ float Bs[BK][64 + 4];
    const int bm = blockIdx.y * 64, bn = blockIdx.x * 64;
    const int tid = threadIdx.x;
    const int tx = tid & 15, ty = tid >> 4;
    const int lr = tid >> 2, lk = (tid & 3) * 8;
    float acc[4][4] = {};

    for (int k0 = 0; k0 < NK; k0 += BK) {
        float va[8], vb[8];
        load8(A + (size_t)(bm + lr) * NK + k0 + lk, va);
        load8(W + (size_t)(bn + lr) * NK + k0 + lk, vb);
#pragma unroll
        for (int i = 0; i < 8; ++i) { As[lk + i][lr] = va[i]; Bs[lk + i][lr] = vb[i]; }
        __syncthreads();
#pragma unroll
        for (int kk = 0; kk < BK; ++kk) {
            float4 a4 = *(const float4*)&As[kk][ty * 4];
            float4 b4 = *(const float4*)&Bs[kk][tx * 4];
            float a[4] = {a4.x, a4.y, a4.z, a4.w};
            float b[4] = {b4.x, b4.y, b4.z, b4.w};
#pragma unroll
            for (int i = 0; i < 4; ++i)
#pragma unroll
                for (int j = 0; j < 4; ++j)
                    acc[i][j] = fmaf(a[i], b[j], acc[i][j]);
        }
        __syncthreads();
    }

    float4 bv = *(const float4*)&bias[bn + tx * 4];
    float bvv[4] = {bv.x, bv.y, bv.z, bv.w};
#pragma unroll
    for (int i = 0; i < 4; ++i) {
        size_t row = (size_t)(bm + ty * 4 + i) * NK + bn + tx * 4;
        float4 o;
        o.x = acc[i][0] + bvv[0];
        o.y = acc[i][1] + bvv[1];
        o.z = acc[i][2] + bvv[2];
        o.w = acc[i][3] + bvv[3];
        *(float4*)&C[row] = o;
    }
}

// ---------- fused: f32 screen (per-lane reg top-24) -> top-32 on the SAME f32 scores -> PV ----------
// Selection is done directly on the screened f32 scores (sequential-d f32 FMA, x0.125f),
// which replicates the references' f32 score bit pattern. No f64 rescore.
// grid (32 qtiles, 8 heads, 8 batches), 256 threads. Wave w, group g=lane/8 owns row 8w+g;
// lane-in-group j handles columns == j (mod 8).
__global__ __launch_bounds__(256) void topk_attn_fused(
    const float* __restrict__ Qf, const float* __restrict__ Kf,
    const float* __restrict__ Vp, float* __restrict__ Xp)
{
    constexpr int LQ = 1024, LM = 4096, DK = 64, D = 512, QT = 32, MT = 64, TK = 32, T = 24;
    // LDS: region A: ks f32[64][68] (17408 B), aliased after screen by wsel f32[32][33] + isel i32[32][33]
    //      region B: qs f32[32][68] (8704 B)
    //      region C: sc f32[32][72] (9216 B)
    __shared__ __align__(16) char smem[17408 + 8704 + 9216];
    float  (*ks)[68]   = (float  (*)[68])(smem);
    float  (*wsel)[33] = (float  (*)[33])(smem);
    int    (*isel)[33] = (int    (*)[33])(smem + 4224);
    float  (*qs)[68]   = (float  (*)[68])(smem + 17408);
    float  (*sc)[72]   = (float  (*)[72])(smem + 17408 + 8704);

    const int tid  = threadIdx.x;
    const int lane = tid & 63;
    const int w    = tid >> 6;
    const int g    = lane >> 3, j = lane & 7;
    const int r    = 8 * w + g;                    // merge row owned by this lane
    const int qt = blockIdx.x, h = blockIdx.y, b = blockIdx.z;

    // stage 32x64 Q tile (f32)
    {
        int rr = tid >> 3, d0 = (tid & 7) * 8;
        const float* src = Qf + ((size_t)(b * LQ + qt * QT + rr) * D + h * DK + d0);
        float4 a = *(const float4*)src;
        float4 c = *(const float4*)(src + 4);
        *(float4*)&qs[rr][d0]     = a;
        *(float4*)&qs[rr][d0 + 4] = c;
    }

    // per-lane top-T registers (fully unrolled access only)
    float bv[T]; int bi[T];
#pragma unroll
    for (int t = 0; t < T; ++t) { bv[t] = -INFINITY; bi[t] = 0; }
    float curmin = -INFINITY; int minpos = 0;

    const int qg = tid >> 5, mg = tid & 31;
    __syncthreads();

#pragma unroll 1
    for (int mc = 0; mc < LM; mc += MT) {
        // stage 64x64 K tile (f32)
        {
            int rr = tid >> 2, d0 = (tid & 3) * 16;
            const float* src = Kf + ((size_t)(b * LM + mc + rr) * D + h * DK + d0);
#pragma unroll
            for (int i = 0; i < 16; i += 4)
                *(float4*)&ks[rr][d0 + i] = *(const float4*)(src + i);
        }
        __syncthreads();

        // 32x64 scores, 4q x 2m per thread, f32, strict ascending-d single-accumulator FMA
        float acc[4][2] = {};
#pragma unroll
        for (int d = 0; d < DK; d += 4) {
            float4 qa[4], kb[2];
#pragma unroll
            for (int i = 0; i < 4; ++i) qa[i] = *(const float4*)&qs[qg + 8 * i][d];
#pragma unroll
            for (int jj = 0; jj < 2; ++jj) kb[jj] = *(const float4*)&ks[mg + 32 * jj][d];
#pragma unroll
            for (int i = 0; i < 4; ++i)
#pragma unroll
                for (int jj = 0; jj < 2; ++jj) {
                    acc[i][jj] = fmaf(qa[i].x, kb[jj].x, acc[i][jj]);
                    acc[i][jj] = fmaf(qa[i].y, kb[jj].y, acc[i][jj]);
                    acc[i][jj] = fmaf(qa[i].z, kb[jj].z, acc[i][jj]);
                    acc[i][jj] = fmaf(qa[i].w, kb[jj].w, acc[i][jj]);
                }
        }
#pragma unroll
        for (int i = 0; i < 4; ++i)
#pragma unroll
            for (int jj = 0; jj < 2; ++jj)
                sc[qg + 8 * i][mg + 32 * jj] = acc[i][jj] * 0.125f;
        __syncthreads();

        // per-lane merge: 8 columns of my row; strict > keeps earliest (lowest) index on ties
#pragma unroll
        for (int c = 0; c < 8; ++c) {
            float v = sc[r][8 * c + j];
            if (v > curmin) {
                int idx = mc + 8 * c + j;
#pragma unroll
                for (int t = 0; t < T; ++t)
                    if (t == minpos) { bv[t] = v; bi[t] = idx; }
                float mv = bv[0]; int mp = 0;
#pragma unroll
                for (int t = 1; t < T; ++t)
                    if (bv[t] < mv) { mv = bv[t]; mp = t; }
                curmin = mv; minpos = mp;
            }
        }
        __syncthreads();
    }

    // exact top-32 among the group's 192 candidates on the f32 screen scores
    // (f32 order, lower index on ties — jax.lax.top_k semantics)
    unsigned cons = 0;
    float m0 = 0.0f;
    double sum_part = 0.0;
#pragma unroll 1
    for (int t32 = 0; t32 < TK; ++t32) {
        float lm = -INFINITY; int li = 0x7fffffff; int lp = -1;
#pragma unroll
        for (int t = 0; t < T; ++t) {
            bool ok = !(cons & (1u << t));
            if (ok && (bv[t] > lm || (bv[t] == lm && bi[t] < li))) {
                lm = bv[t]; li = bi[t]; lp = t;
            }
        }
        float gv = lm; int gi = li;
#pragma unroll
        for (int k = 1; k < 8; k <<= 1) {
            float ov = __shfl_xor(gv, k);
            int   oi = __shfl_xor(gi, k);
            if (ov > gv || (ov == gv && oi < gi)) { gv = ov; gi = oi; }
        }
        if (lp >= 0 && gv == lm && gi == li) cons |= 1u << lp;   // winner's owner consumes
        if (t32 == 0) m0 = gv;
        if ((t32 & 7) == j) {
            double e = exp((double)(gv - m0));
            sum_part += e;
            isel[r][t32] = gi;
            wsel[r][t32] = (float)e;       // unnormalized; rescaled below
        }
    }
#pragma unroll
    for (int k = 1; k < 8; k <<= 1) sum_part += __shfl_xor(sum_part, k);
    {
        double inv = 1.0 / sum_part;
#pragma unroll
        for (int tt = 0; tt < 4; ++tt) {
            int t = 8 * tt + j;
            wsel[r][t] = (float)((double)wsel[r][t] * inv);
        }
    }
    __syncthreads();

    // PV: gather selected V rows (f32), write X[b, q, h*64+d]
    {
        int rr = tid >> 3, d0 = (tid & 7) * 8;
        float4 a0 = {0, 0, 0, 0}, a1 = {0, 0, 0, 0};
#pragma unroll 1
        for (int t = 0; t < TK; ++t) {
            float ww = wsel[rr][t];
            int mi   = isel[rr][t];
            const float* vp = Vp + ((size_t)(b * LM + mi) * D + h * DK + d0);
            float4 v0 = *(const float4*)vp;
            float4 v1 = *(const float4*)(vp + 4);
            a0.x = fmaf(ww, v0.x, a0.x); a0.y = fmaf(ww, v0.y, a0.y);
            a0.z = fmaf(ww, v0.z, a0.z); a0.w = fmaf(ww, v0.w, a0.w);
            a1.x = fmaf(ww, v1.x, a1.x); a1.y = fmaf(ww, v1.y, a1.y);
            a1.z = fmaf(ww, v1.z, a1.z); a1.w = fmaf(ww, v1.w, a1.w);
        }
        float* xp = Xp + ((size_t)(b * LQ + qt * QT + rr) * D + h * DK + d0);
        *(float4*)xp       = a0;
        *(float4*)(xp + 4) = a1;
    }
}

extern "C" void kernel_launch(void* const* d_in, const int* in_sizes, int n_in,
                              void* d_out, int out_size, void* d_ws, size_t ws_size,
                              hipStream_t stream) {
    const float* query = (const float*)d_in[0];
    const float* key   = (const float*)d_in[1];
    const float* value = (const float*)d_in[2];
    const float* Wq    = (const float*)d_in[3];
    const float* bq    = (const float*)d_in[4];
    const float* Wk    = (const float*)d_in[5];
    const float* bk    = (const float*)d_in[6];
    const float* Wv    = (const float*)d_in[7];
    const float* bv    = (const float*)d_in[8];
    const float* Wo    = (const float*)d_in[9];
    const float* bo    = (const float*)d_in[10];
    float* out = (float*)d_out;

    // ws: V f32 [32768,512] | X f32 [8192,512] | Q f32 [8192,512] | K f32 [32768,512]  (~168 MB)
    float* Vp = (float*)d_ws;
    float* Xp = Vp + (size_t)32768 * 512;
    float* Qf = Xp + (size_t)8192 * 512;
    float* Kf = Qf + (size_t)8192 * 512;

    dim3 blk(256);
    gemm_nt512<<<dim3(8, 128), blk, 0, stream>>>(query, Wq, bq, Qf);
    gemm_nt512<<<dim3(8, 512), blk, 0, stream>>>(key,   Wk, bk, Kf);
    gemm_nt512<<<dim3(8, 512), blk, 0, stream>>>(value, Wv, bv, Vp);
    topk_attn_fused<<<dim3(32, 8, 8), blk, 0, stream>>>(Qf, Kf, Vp, Xp);
    gemm_nt512<<<dim3(8, 128), blk, 0, stream>>>(Xp, Wo, bo, out);
}